// Round 3
// baseline (1557.677 us; speedup 1.0000x reference)
//
#include <hip/hip_runtime.h>

#define B_TOTAL 131072
#define PD 200
#define KAPPA 0.8f
#define LAMDA 0.9999f
#define YITA 0.5f
#define MS_KS 216   // M LDS k-stride (27 16B slots, odd -> conflict-free A-frag reads)

typedef short short8 __attribute__((ext_vector_type(8)));
typedef float f32x16 __attribute__((ext_vector_type(16)));

static __device__ __forceinline__ float bf2f(unsigned short h) {
  union { unsigned u; float f; } v; v.u = ((unsigned)h) << 16; return v.f;
}
static __device__ __forceinline__ unsigned short f2bf(float f) {
  union { float f; unsigned u; } v; v.f = f;
  unsigned r = v.u + 0x7FFFu + ((v.u >> 16) & 1u);
  return (unsigned short)(r >> 16);
}
static __device__ __forceinline__ float fp_nl(float v) {  // clip(leaky_relu(v),-1,1)
  float t = fmaxf(v, 0.01f * v);
  return fminf(1.f, fmaxf(-1.f, t));
}
static __device__ __forceinline__ unsigned pkbf(float lo, float hi) {
  unsigned r;
  asm("v_cvt_pk_bf16_f32 %0, %1, %2" : "=v"(r) : "v"(lo), "v"(hi));
  return r;
}
// verified R2: swaps 32-lane halves between a,b (a<-{A.lo,B.lo}, b<-{A.hi,B.hi})
static __device__ __forceinline__ void swap32(unsigned &a, unsigned &b) {
  asm("s_nop 1\n\tv_permlane32_swap_b32 %0, %1" : "+v"(a), "+v"(b));
}
static __device__ __forceinline__ short8 pf2s8(const unsigned* w) {
  union { unsigned u[4]; short8 s; } x;
  x.u[0] = w[0]; x.u[1] = w[1]; x.u[2] = w[2]; x.u[3] = w[3];
  return x.s;
}

__global__ void tem_init_m(const float* __restrict__ Min, float* __restrict__ oM) {
  int i = blockIdx.x * 256 + threadIdx.x;
  if (i < PD * PD) oM[i] = LAMDA * Min[i];
}

// launch_bounds(512, 1): CUDA semantics = min 1 BLOCK/CU -> 8 waves/CU -> 2
// waves/SIMD -> 256-reg unified budget. (512,2) forced 128 VGPRs and spilled
// acc[7] (R2: 1.5 GB symmetric scratch traffic).
__global__ __launch_bounds__(512, 1) void tem_main(
    const float* __restrict__ xin, const float* __restrict__ gin,
    const float* __restrict__ Min, const float* __restrict__ Wc,
    const float* __restrict__ W1ie, const float* __restrict__ b1ie,
    const float* __restrict__ W2ie, const float* __restrict__ b2ie,
    const float* __restrict__ W1gg, const float* __restrict__ b1gg,
    const float* __restrict__ W2gg, const float* __restrict__ b2gg,
    const float* __restrict__ Wsp, const float* __restrict__ bsp,
    float* __restrict__ o_ginf, float* __restrict__ o_xinf,
    float* __restrict__ o_g, float* __restrict__ o_x,
    unsigned short* __restrict__ dWp, unsigned short* __restrict__ sWp) {
  // LDS: 96768 + 5120 + 20480 = 122368 B
  __shared__ __attribute__((aligned(16))) unsigned short Ms[224 * MS_KS];
  __shared__ unsigned short xcS[256 * 10];
  __shared__ float g2S[256 * 20];

  const int tid = threadIdx.x;
  const int lane = tid & 63;
  const int wid = tid >> 6;
  const int cl = lane & 31;
  const int hi = lane >> 5;
  const int r0 = blockIdx.x * 256;

  // zero Ms (u32-wide), then fill M^T + kappa*I as bf16
  {
    unsigned* Ms32 = (unsigned*)Ms;
    for (int i = tid; i < 224 * MS_KS / 2; i += 512) Ms32[i] = 0u;
  }
  __syncthreads();
  for (int i = tid; i < 200 * 224; i += 512) {
    const int k = i / 224, n = i - k * 224;
    if (n < 200) {
      float v = Min[k * 200 + n];
      if (k == n) v += KAPPA;
      Ms[n * MS_KS + k] = f2bf(v);
    }
  }

  // prologue: threads 0..255 -> g2 MLP; 256..511 -> xc
  if (tid < 256) {
    const int r = r0 + tid;
    float gv[20];
#pragma unroll
    for (int i = 0; i < 20; ++i) gv[i] = gin[(size_t)r * 20 + i];
    float h[40];
#pragma unroll
    for (int u = 0; u < 40; ++u) h[u] = b1gg[u];
#pragma unroll
    for (int i = 0; i < 20; ++i)
#pragma unroll
      for (int u = 0; u < 40; ++u) h[u] += gv[i] * W1gg[i * 40 + u];
#pragma unroll
    for (int u = 0; u < 40; ++u) h[u] = (h[u] > 0.f) ? h[u] : (expf(h[u]) - 1.f);
#pragma unroll
    for (int o = 0; o < 20; ++o) {
      float v = b2gg[o];
#pragma unroll
      for (int u = 0; u < 40; ++u) v += h[u] * W2gg[u * 20 + o];
      g2S[tid * 20 + o] = tanhf(v);
    }
  } else {
    const int rr = tid - 256;
    const int r = r0 + rr;
    float xc[10];
#pragma unroll
    for (int o = 0; o < 10; ++o) xc[o] = 0.f;
    for (int j = 0; j < 45; ++j) {
      const float xv = xin[(size_t)r * 45 + j];
#pragma unroll
      for (int o = 0; o < 10; ++o) xc[o] += xv * Wc[j * 10 + o];
    }
#pragma unroll
    for (int o = 0; o < 10; ++o) xcS[rr * 10 + o] = f2bf(xc[o]);
  }
  __syncthreads();

  // P1: write g_ and x_ outputs (coalesced flat loop)
  for (int i = tid; i < 256 * 200; i += 512) {
    const int r = i / 200, j = i - r * 200;
    o_g[(size_t)(r0 + r) * 200 + j] = g2S[r * 20 + j / 10];
    o_x[(size_t)(r0 + r) * 200 + j] = bf2f(xcS[r * 10 + (j % 10)]);
  }

  const int rr = wid * 32 + cl;   // block-row this lane owns
  const int r = r0 + rr;          // global row

  unsigned pf[13][4];             // p^T B-fragments: lane=batch col, k=feature

  for (int ret = 0; ret < 2; ++ret) {
    // ---- build initial fragments
    if (ret == 0) {
      float xcv[10];
#pragma unroll
      for (int o = 0; o < 10; ++o) xcv[o] = bf2f(xcS[rr * 10 + o]);
      if (hi == 0) {
#pragma unroll
        for (int kc = 0; kc < 13; ++kc)
#pragma unroll
          for (int jw = 0; jw < 4; ++jw) {
            const int f0 = kc * 16 + 2 * jw;
            pf[kc][jw] = pkbf(xcv[f0 % 10], xcv[(f0 + 1) % 10]);
          }
      } else {
#pragma unroll
        for (int kc = 0; kc < 12; ++kc)
#pragma unroll
          for (int jw = 0; jw < 4; ++jw) {
            const int f0 = kc * 16 + 8 + 2 * jw;
            pf[kc][jw] = pkbf(xcv[f0 % 10], xcv[(f0 + 1) % 10]);
          }
#pragma unroll
        for (int jw = 0; jw < 4; ++jw) pf[12][jw] = 0u;   // features 200..207
      }
    } else {
      float g2v[20];
#pragma unroll
      for (int o = 0; o < 20; ++o) g2v[o] = g2S[rr * 20 + o];
      if (hi == 0) {
#pragma unroll
        for (int kc = 0; kc < 13; ++kc)
#pragma unroll
          for (int jw = 0; jw < 4; ++jw) {
            const int f0 = kc * 16 + 2 * jw;
            pf[kc][jw] = pkbf(g2v[f0 / 10], g2v[(f0 + 1) / 10]);
          }
      } else {
#pragma unroll
        for (int kc = 0; kc < 12; ++kc)
#pragma unroll
          for (int jw = 0; jw < 4; ++jw) {
            const int f0 = kc * 16 + 8 + 2 * jw;
            pf[kc][jw] = pkbf(g2v[f0 / 10], g2v[(f0 + 1) / 10]);
          }
#pragma unroll
        for (int jw = 0; jw < 4; ++jw) pf[12][jw] = 0u;
      }
    }

    // ---- 5 attractor iterations, fully register-resident
    for (int it = 0; it < 5; ++it) {
      f32x16 acc[7];
#pragma unroll
      for (int nt = 0; nt < 7; ++nt)
#pragma unroll
        for (int q = 0; q < 16; ++q) acc[nt][q] = 0.f;
#pragma unroll
      for (int kc = 0; kc < 13; ++kc) {
        const short8 bfr = pf2s8(pf[kc]);
#pragma unroll
        for (int nt = 0; nt < 7; ++nt) {
          const short8 af = *(const short8*)(Ms + ((nt * 32 + cl) * MS_KS + kc * 16 + hi * 8));
          acc[nt] = __builtin_amdgcn_mfma_f32_32x32x16_bf16(af, bfr, acc[nt], 0, 0, 0);
        }
      }
      // nonlinearity + C-layout -> B-layout repack (cvt_pk + permlane32_swap)
#pragma unroll
      for (int nt = 0; nt < 7; ++nt) {
        float t0 = fp_nl(acc[nt][0]),  t1 = fp_nl(acc[nt][1]);
        float t2 = fp_nl(acc[nt][2]),  t3 = fp_nl(acc[nt][3]);
        float t4 = fp_nl(acc[nt][4]),  t5 = fp_nl(acc[nt][5]);
        float t6 = fp_nl(acc[nt][6]),  t7 = fp_nl(acc[nt][7]);
        unsigned P0 = pkbf(t0, t1), P1 = pkbf(t2, t3);
        unsigned P2 = pkbf(t4, t5), P3 = pkbf(t6, t7);
        swap32(P0, P2);
        swap32(P1, P3);
        pf[2 * nt][0] = P0; pf[2 * nt][1] = P1;
        pf[2 * nt][2] = P2; pf[2 * nt][3] = P3;
        if (nt < 6) {
          float u0 = fp_nl(acc[nt][8]),  u1 = fp_nl(acc[nt][9]);
          float u2 = fp_nl(acc[nt][10]), u3 = fp_nl(acc[nt][11]);
          float u4 = fp_nl(acc[nt][12]), u5 = fp_nl(acc[nt][13]);
          float u6 = fp_nl(acc[nt][14]), u7 = fp_nl(acc[nt][15]);
          unsigned P4 = pkbf(u0, u1), P5 = pkbf(u2, u3);
          unsigned P6 = pkbf(u4, u5), P7 = pkbf(u6, u7);
          swap32(P4, P6);
          swap32(P5, P7);
          pf[2 * nt + 1][0] = P4; pf[2 * nt + 1][1] = P5;
          pf[2 * nt + 1][2] = P6; pf[2 * nt + 1][3] = P7;
        }
      }
    }

    if (ret == 0) {
      // ---- E1: g_inf = clip(MLP(px @ W_repeat^T))
      float bins[20];
#pragma unroll
      for (int t = 0; t < 20; ++t) bins[t] = 0.f;
      if (hi == 0) {
#pragma unroll
        for (int kc = 0; kc < 13; ++kc)
#pragma unroll
          for (int jw = 0; jw < 4; ++jw) {
            const int f0 = kc * 16 + 2 * jw;
            const unsigned w = pf[kc][jw];
            bins[f0 / 10] += bf2f((unsigned short)(w & 0xFFFF));
            bins[(f0 + 1) / 10] += bf2f((unsigned short)(w >> 16));
          }
      } else {
#pragma unroll
        for (int kc = 0; kc < 12; ++kc)
#pragma unroll
          for (int jw = 0; jw < 4; ++jw) {
            const int f0 = kc * 16 + 8 + 2 * jw;
            const unsigned w = pf[kc][jw];
            bins[f0 / 10] += bf2f((unsigned short)(w & 0xFFFF));
            bins[(f0 + 1) / 10] += bf2f((unsigned short)(w >> 16));
          }
      }
#pragma unroll
      for (int t = 0; t < 20; ++t) bins[t] += __shfl_xor(bins[t], 32);
      float h[40];
#pragma unroll
      for (int u = 0; u < 40; ++u) h[u] = b1ie[u];
#pragma unroll
      for (int gg = 0; gg < 20; ++gg) {
        const float bv = bins[gg];
#pragma unroll
        for (int u = 0; u < 40; ++u) h[u] += bv * W1ie[gg * 40 + u];
      }
#pragma unroll
      for (int u = 0; u < 40; ++u) h[u] = (h[u] > 0.f) ? h[u] : (expf(h[u]) - 1.f);
#pragma unroll
      for (int oi = 0; oi < 10; ++oi) {
        const int o = hi * 10 + oi;
        float v = b2ie[o];
#pragma unroll
        for (int u = 0; u < 40; ++u) v += h[u] * W2ie[u * 20 + o];
        o_ginf[(size_t)r * 20 + o] = fminf(1.f, fmaxf(-1.f, v));
      }
    } else {
      // ---- E2a: x_inf = (p @ W_tile^T) @ W_sp + b_sp
      float ta[10];
#pragma unroll
      for (int t = 0; t < 10; ++t) ta[t] = 0.f;
      if (hi == 0) {
#pragma unroll
        for (int kc = 0; kc < 13; ++kc)
#pragma unroll
          for (int jw = 0; jw < 4; ++jw) {
            const int f0 = kc * 16 + 2 * jw;
            const unsigned w = pf[kc][jw];
            ta[f0 % 10] += bf2f((unsigned short)(w & 0xFFFF));
            ta[(f0 + 1) % 10] += bf2f((unsigned short)(w >> 16));
          }
      } else {
#pragma unroll
        for (int kc = 0; kc < 12; ++kc)
#pragma unroll
          for (int jw = 0; jw < 4; ++jw) {
            const int f0 = kc * 16 + 8 + 2 * jw;
            const unsigned w = pf[kc][jw];
            ta[f0 % 10] += bf2f((unsigned short)(w & 0xFFFF));
            ta[(f0 + 1) % 10] += bf2f((unsigned short)(w >> 16));
          }
      }
#pragma unroll
      for (int t = 0; t < 10; ++t) ta[t] += __shfl_xor(ta[t], 32);
      {
        const int o0 = hi ? 23 : 0, o1 = hi ? 45 : 23;
        for (int o = o0; o < o1; ++o) {
          float v = bsp[o];
#pragma unroll
          for (int a = 0; a < 10; ++a) v += ta[a] * Wsp[a * 45 + o];
          o_xinf[(size_t)r * 45 + o] = v;
        }
      }
      // ---- E2b: d/s staging, feature-major [f*B + r] (hebb-fragment-ready)
      {
        float xcv[10], g2v[20];
#pragma unroll
        for (int o = 0; o < 10; ++o) xcv[o] = bf2f(xcS[rr * 10 + o]);
#pragma unroll
        for (int o = 0; o < 20; ++o) g2v[o] = g2S[rr * 20 + o];
        if (hi == 0) {
#pragma unroll
          for (int kc = 0; kc < 13; ++kc)
#pragma unroll
            for (int jw = 0; jw < 4; ++jw) {
              const int f0 = kc * 16 + 2 * jw;
              const unsigned w = pf[kc][jw];
              const float p0 = bf2f((unsigned short)(w & 0xFFFF));
              const float p1 = bf2f((unsigned short)(w >> 16));
              const float pi0 = fp_nl(g2v[f0 / 10] * xcv[f0 % 10]);
              const float pi1 = fp_nl(g2v[(f0 + 1) / 10] * xcv[(f0 + 1) % 10]);
              dWp[(size_t)f0 * B_TOTAL + r] = f2bf(pi0 - p0);
              sWp[(size_t)f0 * B_TOTAL + r] = f2bf(pi0 + p0);
              dWp[(size_t)(f0 + 1) * B_TOTAL + r] = f2bf(pi1 - p1);
              sWp[(size_t)(f0 + 1) * B_TOTAL + r] = f2bf(pi1 + p1);
            }
        } else {
#pragma unroll
          for (int kc = 0; kc < 12; ++kc)
#pragma unroll
            for (int jw = 0; jw < 4; ++jw) {
              const int f0 = kc * 16 + 8 + 2 * jw;
              const unsigned w = pf[kc][jw];
              const float p0 = bf2f((unsigned short)(w & 0xFFFF));
              const float p1 = bf2f((unsigned short)(w >> 16));
              const float pi0 = fp_nl(g2v[f0 / 10] * xcv[f0 % 10]);
              const float pi1 = fp_nl(g2v[(f0 + 1) / 10] * xcv[(f0 + 1) % 10]);
              dWp[(size_t)f0 * B_TOTAL + r] = f2bf(pi0 - p0);
              sWp[(size_t)f0 * B_TOTAL + r] = f2bf(pi0 + p0);
              dWp[(size_t)(f0 + 1) * B_TOTAL + r] = f2bf(pi1 - p1);
              sWp[(size_t)(f0 + 1) * B_TOTAL + r] = f2bf(pi1 + p1);
            }
        }
      }
    }
  }
}

__global__ __launch_bounds__(448, 1) void tem_hebb(
    const unsigned short* __restrict__ dWp, const unsigned short* __restrict__ sWp,
    float* __restrict__ oM) {
  const int tid = threadIdx.x;
  const int lane = tid & 63, wid = tid >> 6;   // 7 waves
  const int cl = lane & 31, hi = lane >> 5;
  f32x16 hacc[7];
#pragma unroll
  for (int nt = 0; nt < 7; ++nt)
#pragma unroll
    for (int q = 0; q < 16; ++q) hacc[nt][q] = 0.f;

  const int fa = wid * 32 + cl;
  const size_t arow = (size_t)fa * B_TOTAL;
  const int kb0 = blockIdx.x * 512;
  const short8 zf = {0, 0, 0, 0, 0, 0, 0, 0};

  for (int kch = 0; kch < 32; ++kch) {
    const int kb = kb0 + kch * 16 + hi * 8;
    short8 a = zf;
    if (fa < 200) a = *(const short8*)(dWp + arow + kb);
#pragma unroll
    for (int nt = 0; nt < 7; ++nt) {
      const int fb = nt * 32 + cl;
      short8 b = zf;
      if (fb < 200) b = *(const short8*)(sWp + (size_t)fb * B_TOTAL + kb);
      hacc[nt] = __builtin_amdgcn_mfma_f32_32x32x16_bf16(a, b, hacc[nt], 0, 0, 0);
    }
  }
  const float scale = YITA / (float)B_TOTAL;
#pragma unroll
  for (int nt = 0; nt < 7; ++nt) {
    const int j = nt * 32 + cl;
    if (j < 200) {
#pragma unroll
      for (int rg = 0; rg < 16; ++rg) {
        const int ii = wid * 32 + (rg & 3) + 8 * (rg >> 2) + 4 * hi;
        if (ii < 200) atomicAdd(&oM[ii * 200 + j], hacc[nt][rg] * scale);
      }
    }
  }
}

extern "C" void kernel_launch(void* const* d_in, const int* in_sizes, int n_in,
                              void* d_out, int out_size, void* d_ws, size_t ws_size,
                              hipStream_t stream) {
  (void)in_sizes; (void)n_in; (void)out_size; (void)ws_size;
  const float* xin  = (const float*)d_in[0];
  const float* gin  = (const float*)d_in[1];
  const float* Min  = (const float*)d_in[2];
  const float* Wc   = (const float*)d_in[3];
  const float* W1ie = (const float*)d_in[4];
  const float* b1ie = (const float*)d_in[5];
  const float* W2ie = (const float*)d_in[6];
  const float* b2ie = (const float*)d_in[7];
  const float* W1gg = (const float*)d_in[8];
  const float* b1gg = (const float*)d_in[9];
  const float* W2gg = (const float*)d_in[10];
  const float* b2gg = (const float*)d_in[11];
  const float* Wsp  = (const float*)d_in[12];
  const float* bsp  = (const float*)d_in[13];

  float* out = (float*)d_out;
  float* o_ginf = out;
  float* o_xinf = out + (size_t)B_TOTAL * 20;
  float* o_g    = out + (size_t)B_TOTAL * 65;
  float* o_x    = out + (size_t)B_TOTAL * 265;
  float* o_M    = out + (size_t)B_TOTAL * 465;

  unsigned short* dWp = (unsigned short*)d_ws;
  unsigned short* sWp = dWp + (size_t)PD * B_TOTAL;

  tem_init_m<<<(PD * PD + 255) / 256, 256, 0, stream>>>(Min, o_M);
  tem_main<<<512, 512, 0, stream>>>(xin, gin, Min, Wc, W1ie, b1ie, W2ie, b2ie,
                                    W1gg, b1gg, W2gg, b2gg, Wsp, bsp,
                                    o_ginf, o_xinf, o_g, o_x, dWp, sWp);
  tem_hebb<<<256, 448, 0, stream>>>(dWp, sWp, o_M);
}

// Round 4
// 1488.578 us; speedup vs baseline: 1.0464x; 1.0464x over previous
//
#include <hip/hip_runtime.h>

#define B_TOTAL 131072
#define PD 200
#define KAPPA 0.8f
#define LAMDA 0.9999f
#define YITA 0.5f
#define MS_KS 216   // M LDS k-stride (27 16B slots, odd -> conflict-free A-frag reads)

typedef short short8 __attribute__((ext_vector_type(8)));
typedef float f32x16 __attribute__((ext_vector_type(16)));
typedef unsigned uint4v __attribute__((ext_vector_type(4)));

static __device__ __forceinline__ float bf2f(unsigned short h) {
  union { unsigned u; float f; } v; v.u = ((unsigned)h) << 16; return v.f;
}
static __device__ __forceinline__ unsigned short f2bf(float f) {
  union { float f; unsigned u; } v; v.f = f;
  unsigned r = v.u + 0x7FFFu + ((v.u >> 16) & 1u);
  return (unsigned short)(r >> 16);
}
static __device__ __forceinline__ float fp_nl(float v) {  // clip(leaky_relu(v),-1,1)
  float t = fmaxf(v, 0.01f * v);
  return fminf(1.f, fmaxf(-1.f, t));
}
static __device__ __forceinline__ unsigned pkbf(float lo, float hi) {
  unsigned r;
  asm("v_cvt_pk_bf16_f32 %0, %1, %2" : "=v"(r) : "v"(lo), "v"(hi));
  return r;
}
// verified R2: swaps 32-lane halves between a,b (a<-{A.lo,B.lo}, b<-{A.hi,B.hi})
static __device__ __forceinline__ void swap32(unsigned &a, unsigned &b) {
  asm("s_nop 1\n\tv_permlane32_swap_b32 %0, %1" : "+v"(a), "+v"(b));
}
static __device__ __forceinline__ uint4v mk4(unsigned a, unsigned b, unsigned c, unsigned d) {
  uint4v v; v[0] = a; v[1] = b; v[2] = c; v[3] = d; return v;
}
// by-VALUE bitcast (no pointer into a local array -> SROA-safe; R2's pf2s8(ptr)
// forced pf[13][4] into scratch => 1.7 GB FETCH. rule #20.)
static __device__ __forceinline__ short8 u4s8(uint4v w) {
  union { uint4v u; short8 s; } x; x.u = w; return x.s;
}

__global__ void tem_init_m(const float* __restrict__ Min, float* __restrict__ oM) {
  int i = blockIdx.x * 256 + threadIdx.x;
  if (i < PD * PD) oM[i] = LAMDA * Min[i];
}

// ---- macro machinery: all fragment state in NAMED registers, literal indices
#define LDMS(nt, kc) (*(const short8*)(Ms + (((nt) * 32 + cl) * MS_KS + (kc) * 16 + hi * 8)))

#define STEP(PF, KC) do { \
  const short8 _b = u4s8(PF); \
  acc0 = __builtin_amdgcn_mfma_f32_32x32x16_bf16(LDMS(0, KC), _b, acc0, 0, 0, 0); \
  acc1 = __builtin_amdgcn_mfma_f32_32x32x16_bf16(LDMS(1, KC), _b, acc1, 0, 0, 0); \
  acc2 = __builtin_amdgcn_mfma_f32_32x32x16_bf16(LDMS(2, KC), _b, acc2, 0, 0, 0); \
  acc3 = __builtin_amdgcn_mfma_f32_32x32x16_bf16(LDMS(3, KC), _b, acc3, 0, 0, 0); \
  acc4 = __builtin_amdgcn_mfma_f32_32x32x16_bf16(LDMS(4, KC), _b, acc4, 0, 0, 0); \
  acc5 = __builtin_amdgcn_mfma_f32_32x32x16_bf16(LDMS(5, KC), _b, acc5, 0, 0, 0); \
  acc6 = __builtin_amdgcn_mfma_f32_32x32x16_bf16(LDMS(6, KC), _b, acc6, 0, 0, 0); \
} while (0)

#define REPACK_LO(ACC, PF) do { \
  unsigned P0 = pkbf(fp_nl(ACC[0]), fp_nl(ACC[1])); \
  unsigned P1 = pkbf(fp_nl(ACC[2]), fp_nl(ACC[3])); \
  unsigned P2 = pkbf(fp_nl(ACC[4]), fp_nl(ACC[5])); \
  unsigned P3 = pkbf(fp_nl(ACC[6]), fp_nl(ACC[7])); \
  swap32(P0, P2); swap32(P1, P3); \
  PF = mk4(P0, P1, P2, P3); \
} while (0)

#define REPACK_HI(ACC, PF) do { \
  unsigned P4 = pkbf(fp_nl(ACC[8]),  fp_nl(ACC[9])); \
  unsigned P5 = pkbf(fp_nl(ACC[10]), fp_nl(ACC[11])); \
  unsigned P6 = pkbf(fp_nl(ACC[12]), fp_nl(ACC[13])); \
  unsigned P7 = pkbf(fp_nl(ACC[14]), fp_nl(ACC[15])); \
  swap32(P4, P6); swap32(P5, P7); \
  PF = mk4(P4, P5, P6, P7); \
} while (0)

// lane (hi,cl) holds features BB..BB+7 of fragment PF, BB = kc*16 (+8 if hi)
#define FOR_LO(M_) M_(pf0,0) M_(pf1,16) M_(pf2,32) M_(pf3,48) M_(pf4,64) M_(pf5,80) \
                   M_(pf6,96) M_(pf7,112) M_(pf8,128) M_(pf9,144) M_(pf10,160) M_(pf11,176) M_(pf12,192)
#define FOR_HI(M_) M_(pf0,8) M_(pf1,24) M_(pf2,40) M_(pf3,56) M_(pf4,72) M_(pf5,88) \
                   M_(pf6,104) M_(pf7,120) M_(pf8,136) M_(pf9,152) M_(pf10,168) M_(pf11,184)
// hi-branch: pf12 would be features 200..207 (zero pad) -> set to 0 / skipped in epilogues

#define INX(PF, BB) PF = mk4( \
  pkbf(xcv[((BB) + 0) % 10], xcv[((BB) + 1) % 10]), \
  pkbf(xcv[((BB) + 2) % 10], xcv[((BB) + 3) % 10]), \
  pkbf(xcv[((BB) + 4) % 10], xcv[((BB) + 5) % 10]), \
  pkbf(xcv[((BB) + 6) % 10], xcv[((BB) + 7) % 10]));
#define ING(PF, BB) PF = mk4( \
  pkbf(g2v[((BB) + 0) / 10], g2v[((BB) + 1) / 10]), \
  pkbf(g2v[((BB) + 2) / 10], g2v[((BB) + 3) / 10]), \
  pkbf(g2v[((BB) + 4) / 10], g2v[((BB) + 5) / 10]), \
  pkbf(g2v[((BB) + 6) / 10], g2v[((BB) + 7) / 10]));

#define E1W(W, F) { bins[(F) / 10] += bf2f((unsigned short)((W) & 0xFFFFu)); \
                    bins[((F) + 1) / 10] += bf2f((unsigned short)((W) >> 16)); }
#define E1PF(PF, BB) { E1W(PF[0], (BB) + 0) E1W(PF[1], (BB) + 2) E1W(PF[2], (BB) + 4) E1W(PF[3], (BB) + 6) }

#define E2AW(W, F) { ta[(F) % 10] += bf2f((unsigned short)((W) & 0xFFFFu)); \
                     ta[((F) + 1) % 10] += bf2f((unsigned short)((W) >> 16)); }
#define E2APF(PF, BB) { E2AW(PF[0], (BB) + 0) E2AW(PF[1], (BB) + 2) E2AW(PF[2], (BB) + 4) E2AW(PF[3], (BB) + 6) }

#define E2BW(W, F) { \
  const float p0_ = bf2f((unsigned short)((W) & 0xFFFFu)); \
  const float p1_ = bf2f((unsigned short)((W) >> 16)); \
  const float q0_ = fp_nl(g2v[(F) / 10] * xcv[(F) % 10]); \
  const float q1_ = fp_nl(g2v[((F) + 1) / 10] * xcv[((F) + 1) % 10]); \
  dWp[(size_t)(F) * B_TOTAL + r] = f2bf(q0_ - p0_); \
  sWp[(size_t)(F) * B_TOTAL + r] = f2bf(q0_ + p0_); \
  dWp[(size_t)((F) + 1) * B_TOTAL + r] = f2bf(q1_ - p1_); \
  sWp[(size_t)((F) + 1) * B_TOTAL + r] = f2bf(q1_ + p1_); \
}
#define E2BPF(PF, BB) { E2BW(PF[0], (BB) + 0) E2BW(PF[1], (BB) + 2) E2BW(PF[2], (BB) + 4) E2BW(PF[3], (BB) + 6) }

__global__ __launch_bounds__(512, 1) void tem_main(
    const float* __restrict__ xin, const float* __restrict__ gin,
    const float* __restrict__ Min, const float* __restrict__ Wc,
    const float* __restrict__ W1ie, const float* __restrict__ b1ie,
    const float* __restrict__ W2ie, const float* __restrict__ b2ie,
    const float* __restrict__ W1gg, const float* __restrict__ b1gg,
    const float* __restrict__ W2gg, const float* __restrict__ b2gg,
    const float* __restrict__ Wsp, const float* __restrict__ bsp,
    float* __restrict__ o_ginf, float* __restrict__ o_xinf,
    float* __restrict__ o_g, float* __restrict__ o_x,
    unsigned short* __restrict__ dWp, unsigned short* __restrict__ sWp) {
  // LDS: 96768 + 5120 + 20480 = 122368 B
  __shared__ __attribute__((aligned(16))) unsigned short Ms[224 * MS_KS];
  __shared__ unsigned short xcS[256 * 10];
  __shared__ float g2S[256 * 20];

  const int tid = threadIdx.x;
  const int lane = tid & 63;
  const int wid = tid >> 6;
  const int cl = lane & 31;
  const int hi = lane >> 5;
  const int r0 = blockIdx.x * 256;

  {
    unsigned* Ms32 = (unsigned*)Ms;
    for (int i = tid; i < 224 * MS_KS / 2; i += 512) Ms32[i] = 0u;
  }
  __syncthreads();
  for (int i = tid; i < 200 * 224; i += 512) {
    const int k = i / 224, n = i - k * 224;
    if (n < 200) {
      float v = Min[k * 200 + n];
      if (k == n) v += KAPPA;
      Ms[n * MS_KS + k] = f2bf(v);
    }
  }

  // prologue: threads 0..255 -> g2 MLP; 256..511 -> xc
  if (tid < 256) {
    const int r = r0 + tid;
    float gv[20];
#pragma unroll
    for (int i = 0; i < 20; ++i) gv[i] = gin[(size_t)r * 20 + i];
    float h[40];
#pragma unroll
    for (int u = 0; u < 40; ++u) h[u] = b1gg[u];
#pragma unroll
    for (int i = 0; i < 20; ++i)
#pragma unroll
      for (int u = 0; u < 40; ++u) h[u] += gv[i] * W1gg[i * 40 + u];
#pragma unroll
    for (int u = 0; u < 40; ++u) h[u] = (h[u] > 0.f) ? h[u] : (expf(h[u]) - 1.f);
#pragma unroll
    for (int o = 0; o < 20; ++o) {
      float v = b2gg[o];
#pragma unroll
      for (int u = 0; u < 40; ++u) v += h[u] * W2gg[u * 20 + o];
      g2S[tid * 20 + o] = tanhf(v);
    }
  } else {
    const int rr2 = tid - 256;
    const int r = r0 + rr2;
    float xc[10];
#pragma unroll
    for (int o = 0; o < 10; ++o) xc[o] = 0.f;
    for (int j = 0; j < 45; ++j) {
      const float xv = xin[(size_t)r * 45 + j];
#pragma unroll
      for (int o = 0; o < 10; ++o) xc[o] += xv * Wc[j * 10 + o];
    }
#pragma unroll
    for (int o = 0; o < 10; ++o) xcS[rr2 * 10 + o] = f2bf(xc[o]);
  }
  __syncthreads();

  // P1: write g_ and x_ outputs
  for (int i = tid; i < 256 * 200; i += 512) {
    const int rP = i / 200, j = i - rP * 200;
    o_g[(size_t)(r0 + rP) * 200 + j] = g2S[rP * 20 + j / 10];
    o_x[(size_t)(r0 + rP) * 200 + j] = bf2f(xcS[rP * 10 + (j % 10)]);
  }

  const int rr = wid * 32 + cl;   // block-row this lane owns
  const int r = r0 + rr;          // global row

  uint4v pf0, pf1, pf2, pf3, pf4, pf5, pf6, pf7, pf8, pf9, pf10, pf11, pf12;

  for (int ret = 0; ret < 2; ++ret) {
    // ---- build initial fragments (named regs, literal indices)
    if (ret == 0) {
      float xcv[10];
#pragma unroll
      for (int o = 0; o < 10; ++o) xcv[o] = bf2f(xcS[rr * 10 + o]);
      if (hi == 0) { FOR_LO(INX) }
      else         { FOR_HI(INX) pf12 = mk4(0u, 0u, 0u, 0u); }
    } else {
      float g2v[20];
#pragma unroll
      for (int o = 0; o < 20; ++o) g2v[o] = g2S[rr * 20 + o];
      if (hi == 0) { FOR_LO(ING) }
      else         { FOR_HI(ING) pf12 = mk4(0u, 0u, 0u, 0u); }
    }

    // ---- 5 attractor iterations, fully register-resident
    for (int it = 0; it < 5; ++it) {
      f32x16 acc0 = {}, acc1 = {}, acc2 = {}, acc3 = {}, acc4 = {}, acc5 = {}, acc6 = {};
      STEP(pf0, 0);  STEP(pf1, 1);  STEP(pf2, 2);  STEP(pf3, 3);
      STEP(pf4, 4);  STEP(pf5, 5);  STEP(pf6, 6);  STEP(pf7, 7);
      STEP(pf8, 8);  STEP(pf9, 9);  STEP(pf10, 10); STEP(pf11, 11);
      STEP(pf12, 12);
      REPACK_LO(acc0, pf0);  REPACK_HI(acc0, pf1);
      REPACK_LO(acc1, pf2);  REPACK_HI(acc1, pf3);
      REPACK_LO(acc2, pf4);  REPACK_HI(acc2, pf5);
      REPACK_LO(acc3, pf6);  REPACK_HI(acc3, pf7);
      REPACK_LO(acc4, pf8);  REPACK_HI(acc4, pf9);
      REPACK_LO(acc5, pf10); REPACK_HI(acc5, pf11);
      REPACK_LO(acc6, pf12);              // hi half of tile 6 (n=208..223) dropped
    }

    if (ret == 0) {
      // ---- E1: g_inf = clip(MLP(px @ W_repeat^T))
      float bins[20];
#pragma unroll
      for (int t = 0; t < 20; ++t) bins[t] = 0.f;
      if (hi == 0) { FOR_LO(E1PF) } else { FOR_HI(E1PF) }
#pragma unroll
      for (int t = 0; t < 20; ++t) bins[t] += __shfl_xor(bins[t], 32);
      float h[40];
#pragma unroll
      for (int u = 0; u < 40; ++u) h[u] = b1ie[u];
#pragma unroll
      for (int gg = 0; gg < 20; ++gg) {
        const float bv = bins[gg];
#pragma unroll
        for (int u = 0; u < 40; ++u) h[u] += bv * W1ie[gg * 40 + u];
      }
#pragma unroll
      for (int u = 0; u < 40; ++u) h[u] = (h[u] > 0.f) ? h[u] : (expf(h[u]) - 1.f);
#pragma unroll
      for (int oi = 0; oi < 10; ++oi) {
        const int o = hi * 10 + oi;
        float v = b2ie[o];
#pragma unroll
        for (int u = 0; u < 40; ++u) v += h[u] * W2ie[u * 20 + o];
        o_ginf[(size_t)r * 20 + o] = fminf(1.f, fmaxf(-1.f, v));
      }
    } else {
      // ---- E2a: x_inf = (p @ W_tile^T) @ W_sp + b_sp
      float ta[10];
#pragma unroll
      for (int t = 0; t < 10; ++t) ta[t] = 0.f;
      if (hi == 0) { FOR_LO(E2APF) } else { FOR_HI(E2APF) }
#pragma unroll
      for (int t = 0; t < 10; ++t) ta[t] += __shfl_xor(ta[t], 32);
      {
        const int o0 = hi ? 23 : 0, o1 = hi ? 45 : 23;
        for (int o = o0; o < o1; ++o) {
          float v = bsp[o];
#pragma unroll
          for (int a = 0; a < 10; ++a) v += ta[a] * Wsp[a * 45 + o];
          o_xinf[(size_t)r * 45 + o] = v;
        }
      }
      // ---- E2b: d/s staging, feature-major [f*B + r]
      {
        float xcv[10], g2v[20];
#pragma unroll
        for (int o = 0; o < 10; ++o) xcv[o] = bf2f(xcS[rr * 10 + o]);
#pragma unroll
        for (int o = 0; o < 20; ++o) g2v[o] = g2S[rr * 20 + o];
        if (hi == 0) { FOR_LO(E2BPF) } else { FOR_HI(E2BPF) }
      }
    }
  }
}

__global__ __launch_bounds__(448, 1) void tem_hebb(
    const unsigned short* __restrict__ dWp, const unsigned short* __restrict__ sWp,
    float* __restrict__ oM) {
  const int tid = threadIdx.x;
  const int lane = tid & 63, wid = tid >> 6;   // 7 waves
  const int cl = lane & 31, hi = lane >> 5;
  f32x16 hacc[7];
#pragma unroll
  for (int nt = 0; nt < 7; ++nt)
#pragma unroll
    for (int q = 0; q < 16; ++q) hacc[nt][q] = 0.f;

  const int fa = wid * 32 + cl;
  const size_t arow = (size_t)fa * B_TOTAL;
  const int kb0 = blockIdx.x * 512;
  const short8 zf = {0, 0, 0, 0, 0, 0, 0, 0};

  for (int kch = 0; kch < 32; ++kch) {
    const int kb = kb0 + kch * 16 + hi * 8;
    short8 a = zf;
    if (fa < 200) a = *(const short8*)(dWp + arow + kb);
#pragma unroll
    for (int nt = 0; nt < 7; ++nt) {
      const int fb = nt * 32 + cl;
      short8 b = zf;
      if (fb < 200) b = *(const short8*)(sWp + (size_t)fb * B_TOTAL + kb);
      hacc[nt] = __builtin_amdgcn_mfma_f32_32x32x16_bf16(a, b, hacc[nt], 0, 0, 0);
    }
  }
  const float scale = YITA / (float)B_TOTAL;
#pragma unroll
  for (int nt = 0; nt < 7; ++nt) {
    const int j = nt * 32 + cl;
    if (j < 200) {
#pragma unroll
      for (int rg = 0; rg < 16; ++rg) {
        const int ii = wid * 32 + (rg & 3) + 8 * (rg >> 2) + 4 * hi;
        if (ii < 200) atomicAdd(&oM[ii * 200 + j], hacc[nt][rg] * scale);
      }
    }
  }
}

extern "C" void kernel_launch(void* const* d_in, const int* in_sizes, int n_in,
                              void* d_out, int out_size, void* d_ws, size_t ws_size,
                              hipStream_t stream) {
  (void)in_sizes; (void)n_in; (void)out_size; (void)ws_size;
  const float* xin  = (const float*)d_in[0];
  const float* gin  = (const float*)d_in[1];
  const float* Min  = (const float*)d_in[2];
  const float* Wc   = (const float*)d_in[3];
  const float* W1ie = (const float*)d_in[4];
  const float* b1ie = (const float*)d_in[5];
  const float* W2ie = (const float*)d_in[6];
  const float* b2ie = (const float*)d_in[7];
  const float* W1gg = (const float*)d_in[8];
  const float* b1gg = (const float*)d_in[9];
  const float* W2gg = (const float*)d_in[10];
  const float* b2gg = (const float*)d_in[11];
  const float* Wsp  = (const float*)d_in[12];
  const float* bsp  = (const float*)d_in[13];

  float* out = (float*)d_out;
  float* o_ginf = out;
  float* o_xinf = out + (size_t)B_TOTAL * 20;
  float* o_g    = out + (size_t)B_TOTAL * 65;
  float* o_x    = out + (size_t)B_TOTAL * 265;
  float* o_M    = out + (size_t)B_TOTAL * 465;

  unsigned short* dWp = (unsigned short*)d_ws;
  unsigned short* sWp = dWp + (size_t)PD * B_TOTAL;

  tem_init_m<<<(PD * PD + 255) / 256, 256, 0, stream>>>(Min, o_M);
  tem_main<<<512, 512, 0, stream>>>(xin, gin, Min, Wc, W1ie, b1ie, W2ie, b2ie,
                                    W1gg, b1gg, W2gg, b2gg, Wsp, bsp,
                                    o_ginf, o_xinf, o_g, o_x, dWp, sWp);
  tem_hebb<<<256, 448, 0, stream>>>(dWp, sWp, o_M);
}

// Round 5
// 1303.198 us; speedup vs baseline: 1.1953x; 1.1422x over previous
//
#include <hip/hip_runtime.h>

#define B_TOTAL 131072
#define PD 200
#define KAPPA 0.8f
#define LAMDA 0.9999f
#define YITA 0.5f
#define MS_KS 216   // M LDS k-stride (27 16B slots, odd -> conflict-free A-frag reads)

typedef short short8 __attribute__((ext_vector_type(8)));
typedef float f32x16 __attribute__((ext_vector_type(16)));
typedef unsigned uint4v __attribute__((ext_vector_type(4)));

static __device__ __forceinline__ float bf2f(unsigned short h) {
  union { unsigned u; float f; } v; v.u = ((unsigned)h) << 16; return v.f;
}
static __device__ __forceinline__ unsigned short f2bf(float f) {
  union { float f; unsigned u; } v; v.f = f;
  unsigned r = v.u + 0x7FFFu + ((v.u >> 16) & 1u);
  return (unsigned short)(r >> 16);
}
static __device__ __forceinline__ float fp_nl(float v) {  // clip(leaky_relu(v),-1,1)
  float t = fmaxf(v, 0.01f * v);
  return fminf(1.f, fmaxf(-1.f, t));
}
static __device__ __forceinline__ unsigned pkbf(float lo, float hi) {
  unsigned r;
  asm("v_cvt_pk_bf16_f32 %0, %1, %2" : "=v"(r) : "v"(lo), "v"(hi));
  return r;
}
// verified R2: swaps 32-lane halves between a,b (a<-{A.lo,B.lo}, b<-{A.hi,B.hi})
static __device__ __forceinline__ void swap32(unsigned &a, unsigned &b) {
  asm("s_nop 1\n\tv_permlane32_swap_b32 %0, %1" : "+v"(a), "+v"(b));
}
static __device__ __forceinline__ uint4v mk4(unsigned a, unsigned b, unsigned c, unsigned d) {
  uint4v v; v[0] = a; v[1] = b; v[2] = c; v[3] = d; return v;
}
static __device__ __forceinline__ short8 u4s8(uint4v w) {
  union { uint4v u; short8 s; } x; x.u = w; return x.s;
}

__global__ void tem_init_m(const float* __restrict__ Min, float* __restrict__ oM) {
  int i = blockIdx.x * 256 + threadIdx.x;
  if (i < PD * PD) oM[i] = LAMDA * Min[i];
}

// ---- macro machinery: all fragment state in NAMED registers, literal indices
#define LDMS(nt, kc) (*(const short8*)(Ms + (((nt) * 32 + cl) * MS_KS + (kc) * 16 + hi * 8)))

#define STEP(PF, KC) do { \
  const short8 _b = u4s8(PF); \
  acc0 = __builtin_amdgcn_mfma_f32_32x32x16_bf16(LDMS(0, KC), _b, acc0, 0, 0, 0); \
  acc1 = __builtin_amdgcn_mfma_f32_32x32x16_bf16(LDMS(1, KC), _b, acc1, 0, 0, 0); \
  acc2 = __builtin_amdgcn_mfma_f32_32x32x16_bf16(LDMS(2, KC), _b, acc2, 0, 0, 0); \
  acc3 = __builtin_amdgcn_mfma_f32_32x32x16_bf16(LDMS(3, KC), _b, acc3, 0, 0, 0); \
  acc4 = __builtin_amdgcn_mfma_f32_32x32x16_bf16(LDMS(4, KC), _b, acc4, 0, 0, 0); \
  acc5 = __builtin_amdgcn_mfma_f32_32x32x16_bf16(LDMS(5, KC), _b, acc5, 0, 0, 0); \
  acc6 = __builtin_amdgcn_mfma_f32_32x32x16_bf16(LDMS(6, KC), _b, acc6, 0, 0, 0); \
} while (0)

#define REPACK_LO(ACC, PF) do { \
  unsigned P0 = pkbf(fp_nl(ACC[0]), fp_nl(ACC[1])); \
  unsigned P1 = pkbf(fp_nl(ACC[2]), fp_nl(ACC[3])); \
  unsigned P2 = pkbf(fp_nl(ACC[4]), fp_nl(ACC[5])); \
  unsigned P3 = pkbf(fp_nl(ACC[6]), fp_nl(ACC[7])); \
  swap32(P0, P2); swap32(P1, P3); \
  PF = mk4(P0, P1, P2, P3); \
} while (0)

#define REPACK_HI(ACC, PF) do { \
  unsigned P4 = pkbf(fp_nl(ACC[8]),  fp_nl(ACC[9])); \
  unsigned P5 = pkbf(fp_nl(ACC[10]), fp_nl(ACC[11])); \
  unsigned P6 = pkbf(fp_nl(ACC[12]), fp_nl(ACC[13])); \
  unsigned P7 = pkbf(fp_nl(ACC[14]), fp_nl(ACC[15])); \
  swap32(P4, P6); swap32(P5, P7); \
  PF = mk4(P4, P5, P6, P7); \
} while (0)

// lane (hi,cl) holds features BB..BB+7 of fragment PF, BB = kc*16 (+8 if hi)
#define FOR_LO(M_) M_(pf0,0) M_(pf1,16) M_(pf2,32) M_(pf3,48) M_(pf4,64) M_(pf5,80) \
                   M_(pf6,96) M_(pf7,112) M_(pf8,128) M_(pf9,144) M_(pf10,160) M_(pf11,176) M_(pf12,192)
#define FOR_HI(M_) M_(pf0,8) M_(pf1,24) M_(pf2,40) M_(pf3,56) M_(pf4,72) M_(pf5,88) \
                   M_(pf6,104) M_(pf7,120) M_(pf8,136) M_(pf9,152) M_(pf10,168) M_(pf11,184)
// hi-branch: pf12 would be features 200..207 (zero pad) -> set to 0 / skipped in epilogues

#define INX(PF, BB) PF = mk4( \
  pkbf(xcv[((BB) + 0) % 10], xcv[((BB) + 1) % 10]), \
  pkbf(xcv[((BB) + 2) % 10], xcv[((BB) + 3) % 10]), \
  pkbf(xcv[((BB) + 4) % 10], xcv[((BB) + 5) % 10]), \
  pkbf(xcv[((BB) + 6) % 10], xcv[((BB) + 7) % 10]));
#define ING(PF, BB) PF = mk4( \
  pkbf(g2v[((BB) + 0) / 10], g2v[((BB) + 1) / 10]), \
  pkbf(g2v[((BB) + 2) / 10], g2v[((BB) + 3) / 10]), \
  pkbf(g2v[((BB) + 4) / 10], g2v[((BB) + 5) / 10]), \
  pkbf(g2v[((BB) + 6) / 10], g2v[((BB) + 7) / 10]));

#define E1W(W, F) { bins[(F) / 10] += bf2f((unsigned short)((W) & 0xFFFFu)); \
                    bins[((F) + 1) / 10] += bf2f((unsigned short)((W) >> 16)); }
#define E1PF(PF, BB) { E1W(PF[0], (BB) + 0) E1W(PF[1], (BB) + 2) E1W(PF[2], (BB) + 4) E1W(PF[3], (BB) + 6) }

#define E2AW(W, F) { ta[(F) % 10] += bf2f((unsigned short)((W) & 0xFFFFu)); \
                     ta[((F) + 1) % 10] += bf2f((unsigned short)((W) >> 16)); }
#define E2APF(PF, BB) { E2AW(PF[0], (BB) + 0) E2AW(PF[1], (BB) + 2) E2AW(PF[2], (BB) + 4) E2AW(PF[3], (BB) + 6) }

#define E2BW(W, F) { \
  const float p0_ = bf2f((unsigned short)((W) & 0xFFFFu)); \
  const float p1_ = bf2f((unsigned short)((W) >> 16)); \
  const float q0_ = fp_nl(g2v[(F) / 10] * xcv[(F) % 10]); \
  const float q1_ = fp_nl(g2v[((F) + 1) / 10] * xcv[((F) + 1) % 10]); \
  dWp[(size_t)(F) * B_TOTAL + r] = f2bf(q0_ - p0_); \
  sWp[(size_t)(F) * B_TOTAL + r] = f2bf(q0_ + p0_); \
  dWp[(size_t)((F) + 1) * B_TOTAL + r] = f2bf(q1_ - p1_); \
  sWp[(size_t)((F) + 1) * B_TOTAL + r] = f2bf(q1_ + p1_); \
}
#define E2BPF(PF, BB) { E2BW(PF[0], (BB) + 0) E2BW(PF[1], (BB) + 2) E2BW(PF[2], (BB) + 4) E2BW(PF[3], (BB) + 6) }

// 256 threads (4 waves): single workgroup = 1 wave/SIMD -> full 512-reg unified
// budget (R1 empirically: 208 VGPR, no scratch). 512-thread blocks pin the
// compiler to a 128-reg/wave budget (R2-R4: acc spilled, 1.7 GB scratch traffic).
__global__ __launch_bounds__(256, 1) void tem_main(
    const float* __restrict__ xin, const float* __restrict__ gin,
    const float* __restrict__ Min, const float* __restrict__ Wc,
    const float* __restrict__ W1ie, const float* __restrict__ b1ie,
    const float* __restrict__ W2ie, const float* __restrict__ b2ie,
    const float* __restrict__ W1gg, const float* __restrict__ b1gg,
    const float* __restrict__ W2gg, const float* __restrict__ b2gg,
    const float* __restrict__ Wsp, const float* __restrict__ bsp,
    float* __restrict__ o_ginf, float* __restrict__ o_xinf,
    float* __restrict__ o_g, float* __restrict__ o_x,
    unsigned short* __restrict__ dWp, unsigned short* __restrict__ sWp) {
  // LDS: 96768 + 2560 + 10240 = 109568 B
  __shared__ __attribute__((aligned(16))) unsigned short Ms[224 * MS_KS];
  __shared__ unsigned short xcS[128 * 10];
  __shared__ float g2S[128 * 20];

  const int tid = threadIdx.x;
  const int lane = tid & 63;
  const int wid = tid >> 6;      // 0..3
  const int cl = lane & 31;
  const int hi = lane >> 5;
  const int r0 = blockIdx.x * 128;

  {
    unsigned* Ms32 = (unsigned*)Ms;
    for (int i = tid; i < 224 * MS_KS / 2; i += 256) Ms32[i] = 0u;
  }
  __syncthreads();
  for (int i = tid; i < 200 * 224; i += 256) {
    const int k = i / 224, n = i - k * 224;
    if (n < 200) {
      float v = Min[k * 200 + n];
      if (k == n) v += KAPPA;
      Ms[n * MS_KS + k] = f2bf(v);
    }
  }

  // prologue: threads 0..127 -> g2 MLP; 128..255 -> xc
  if (tid < 128) {
    const int r = r0 + tid;
    float gv[20];
#pragma unroll
    for (int i = 0; i < 20; ++i) gv[i] = gin[(size_t)r * 20 + i];
    float h[40];
#pragma unroll
    for (int u = 0; u < 40; ++u) h[u] = b1gg[u];
#pragma unroll
    for (int i = 0; i < 20; ++i)
#pragma unroll
      for (int u = 0; u < 40; ++u) h[u] += gv[i] * W1gg[i * 40 + u];
#pragma unroll
    for (int u = 0; u < 40; ++u) h[u] = (h[u] > 0.f) ? h[u] : (expf(h[u]) - 1.f);
#pragma unroll
    for (int o = 0; o < 20; ++o) {
      float v = b2gg[o];
#pragma unroll
      for (int u = 0; u < 40; ++u) v += h[u] * W2gg[u * 20 + o];
      g2S[tid * 20 + o] = tanhf(v);
    }
  } else {
    const int rr2 = tid - 128;
    const int r = r0 + rr2;
    float xc[10];
#pragma unroll
    for (int o = 0; o < 10; ++o) xc[o] = 0.f;
    for (int j = 0; j < 45; ++j) {
      const float xv = xin[(size_t)r * 45 + j];
#pragma unroll
      for (int o = 0; o < 10; ++o) xc[o] += xv * Wc[j * 10 + o];
    }
#pragma unroll
    for (int o = 0; o < 10; ++o) xcS[rr2 * 10 + o] = f2bf(xc[o]);
  }
  __syncthreads();

  // P1: write g_ and x_ outputs
  for (int i = tid; i < 128 * 200; i += 256) {
    const int rP = i / 200, j = i - rP * 200;
    o_g[(size_t)(r0 + rP) * 200 + j] = g2S[rP * 20 + j / 10];
    o_x[(size_t)(r0 + rP) * 200 + j] = bf2f(xcS[rP * 10 + (j % 10)]);
  }

  const int rr = wid * 32 + cl;   // block-row this lane owns (0..127)
  const int r = r0 + rr;          // global row

  uint4v pf0, pf1, pf2, pf3, pf4, pf5, pf6, pf7, pf8, pf9, pf10, pf11, pf12;

  for (int ret = 0; ret < 2; ++ret) {
    // ---- build initial fragments (named regs, literal indices)
    if (ret == 0) {
      float xcv[10];
#pragma unroll
      for (int o = 0; o < 10; ++o) xcv[o] = bf2f(xcS[rr * 10 + o]);
      if (hi == 0) { FOR_LO(INX) }
      else         { FOR_HI(INX) pf12 = mk4(0u, 0u, 0u, 0u); }
    } else {
      float g2v[20];
#pragma unroll
      for (int o = 0; o < 20; ++o) g2v[o] = g2S[rr * 20 + o];
      if (hi == 0) { FOR_LO(ING) }
      else         { FOR_HI(ING) pf12 = mk4(0u, 0u, 0u, 0u); }
    }

    // ---- 5 attractor iterations, fully register-resident
    for (int it = 0; it < 5; ++it) {
      f32x16 acc0 = {}, acc1 = {}, acc2 = {}, acc3 = {}, acc4 = {}, acc5 = {}, acc6 = {};
      STEP(pf0, 0);  STEP(pf1, 1);  STEP(pf2, 2);  STEP(pf3, 3);
      STEP(pf4, 4);  STEP(pf5, 5);  STEP(pf6, 6);  STEP(pf7, 7);
      STEP(pf8, 8);  STEP(pf9, 9);  STEP(pf10, 10); STEP(pf11, 11);
      STEP(pf12, 12);
      REPACK_LO(acc0, pf0);  REPACK_HI(acc0, pf1);
      REPACK_LO(acc1, pf2);  REPACK_HI(acc1, pf3);
      REPACK_LO(acc2, pf4);  REPACK_HI(acc2, pf5);
      REPACK_LO(acc3, pf6);  REPACK_HI(acc3, pf7);
      REPACK_LO(acc4, pf8);  REPACK_HI(acc4, pf9);
      REPACK_LO(acc5, pf10); REPACK_HI(acc5, pf11);
      REPACK_LO(acc6, pf12);              // hi half of tile 6 (n=208..223) dropped
    }

    if (ret == 0) {
      // ---- E1: g_inf = clip(MLP(px @ W_repeat^T))
      float bins[20];
#pragma unroll
      for (int t = 0; t < 20; ++t) bins[t] = 0.f;
      if (hi == 0) { FOR_LO(E1PF) } else { FOR_HI(E1PF) }
#pragma unroll
      for (int t = 0; t < 20; ++t) bins[t] += __shfl_xor(bins[t], 32);
      float h[40];
#pragma unroll
      for (int u = 0; u < 40; ++u) h[u] = b1ie[u];
#pragma unroll
      for (int gg = 0; gg < 20; ++gg) {
        const float bv = bins[gg];
#pragma unroll
        for (int u = 0; u < 40; ++u) h[u] += bv * W1ie[gg * 40 + u];
      }
#pragma unroll
      for (int u = 0; u < 40; ++u) h[u] = (h[u] > 0.f) ? h[u] : (expf(h[u]) - 1.f);
#pragma unroll
      for (int oi = 0; oi < 10; ++oi) {
        const int o = hi * 10 + oi;
        float v = b2ie[o];
#pragma unroll
        for (int u = 0; u < 40; ++u) v += h[u] * W2ie[u * 20 + o];
        o_ginf[(size_t)r * 20 + o] = fminf(1.f, fmaxf(-1.f, v));
      }
    } else {
      // ---- E2a: x_inf = (p @ W_tile^T) @ W_sp + b_sp
      float ta[10];
#pragma unroll
      for (int t = 0; t < 10; ++t) ta[t] = 0.f;
      if (hi == 0) { FOR_LO(E2APF) } else { FOR_HI(E2APF) }
#pragma unroll
      for (int t = 0; t < 10; ++t) ta[t] += __shfl_xor(ta[t], 32);
      {
        const int o0 = hi ? 23 : 0, o1 = hi ? 45 : 23;
        for (int o = o0; o < o1; ++o) {
          float v = bsp[o];
#pragma unroll
          for (int a = 0; a < 10; ++a) v += ta[a] * Wsp[a * 45 + o];
          o_xinf[(size_t)r * 45 + o] = v;
        }
      }
      // ---- E2b: d/s staging, feature-major [f*B + r]
      {
        float xcv[10], g2v[20];
#pragma unroll
        for (int o = 0; o < 10; ++o) xcv[o] = bf2f(xcS[rr * 10 + o]);
#pragma unroll
        for (int o = 0; o < 20; ++o) g2v[o] = g2S[rr * 20 + o];
        if (hi == 0) { FOR_LO(E2BPF) } else { FOR_HI(E2BPF) }
      }
    }
  }
}

__global__ __launch_bounds__(448, 1) void tem_hebb(
    const unsigned short* __restrict__ dWp, const unsigned short* __restrict__ sWp,
    float* __restrict__ oM) {
  const int tid = threadIdx.x;
  const int lane = tid & 63, wid = tid >> 6;   // 7 waves
  const int cl = lane & 31, hi = lane >> 5;
  f32x16 hacc[7];
#pragma unroll
  for (int nt = 0; nt < 7; ++nt)
#pragma unroll
    for (int q = 0; q < 16; ++q) hacc[nt][q] = 0.f;

  const int fa = wid * 32 + cl;
  const size_t arow = (size_t)fa * B_TOTAL;
  const int kb0 = blockIdx.x * 512;
  const short8 zf = {0, 0, 0, 0, 0, 0, 0, 0};

  for (int kch = 0; kch < 32; ++kch) {
    const int kb = kb0 + kch * 16 + hi * 8;
    short8 a = zf;
    if (fa < 200) a = *(const short8*)(dWp + arow + kb);
#pragma unroll
    for (int nt = 0; nt < 7; ++nt) {
      const int fb = nt * 32 + cl;
      short8 b = zf;
      if (fb < 200) b = *(const short8*)(sWp + (size_t)fb * B_TOTAL + kb);
      hacc[nt] = __builtin_amdgcn_mfma_f32_32x32x16_bf16(a, b, hacc[nt], 0, 0, 0);
    }
  }
  const float scale = YITA / (float)B_TOTAL;
#pragma unroll
  for (int nt = 0; nt < 7; ++nt) {
    const int j = nt * 32 + cl;
    if (j < 200) {
#pragma unroll
      for (int rg = 0; rg < 16; ++rg) {
        const int ii = wid * 32 + (rg & 3) + 8 * (rg >> 2) + 4 * hi;
        if (ii < 200) atomicAdd(&oM[ii * 200 + j], hacc[nt][rg] * scale);
      }
    }
  }
}

extern "C" void kernel_launch(void* const* d_in, const int* in_sizes, int n_in,
                              void* d_out, int out_size, void* d_ws, size_t ws_size,
                              hipStream_t stream) {
  (void)in_sizes; (void)n_in; (void)out_size; (void)ws_size;
  const float* xin  = (const float*)d_in[0];
  const float* gin  = (const float*)d_in[1];
  const float* Min  = (const float*)d_in[2];
  const float* Wc   = (const float*)d_in[3];
  const float* W1ie = (const float*)d_in[4];
  const float* b1ie = (const float*)d_in[5];
  const float* W2ie = (const float*)d_in[6];
  const float* b2ie = (const float*)d_in[7];
  const float* W1gg = (const float*)d_in[8];
  const float* b1gg = (const float*)d_in[9];
  const float* W2gg = (const float*)d_in[10];
  const float* b2gg = (const float*)d_in[11];
  const float* Wsp  = (const float*)d_in[12];
  const float* bsp  = (const float*)d_in[13];

  float* out = (float*)d_out;
  float* o_ginf = out;
  float* o_xinf = out + (size_t)B_TOTAL * 20;
  float* o_g    = out + (size_t)B_TOTAL * 65;
  float* o_x    = out + (size_t)B_TOTAL * 265;
  float* o_M    = out + (size_t)B_TOTAL * 465;

  unsigned short* dWp = (unsigned short*)d_ws;
  unsigned short* sWp = dWp + (size_t)PD * B_TOTAL;

  tem_init_m<<<(PD * PD + 255) / 256, 256, 0, stream>>>(Min, o_M);
  tem_main<<<1024, 256, 0, stream>>>(xin, gin, Min, Wc, W1ie, b1ie, W2ie, b2ie,
                                     W1gg, b1gg, W2gg, b2gg, Wsp, bsp,
                                     o_ginf, o_xinf, o_g, o_x, dWp, sWp);
  tem_hebb<<<256, 448, 0, stream>>>(dWp, sWp, o_M);
}

// Round 6
// 1196.788 us; speedup vs baseline: 1.3015x; 1.0889x over previous
//
#include <hip/hip_runtime.h>

#define B_TOTAL 131072
#define PD 200
#define KAPPA 0.8f
#define LAMDA 0.9999f
#define YITA 0.5f
#define MS_KS 216   // M LDS k-stride (27 16B slots, odd -> conflict-free A-frag reads)

typedef short short8 __attribute__((ext_vector_type(8)));
typedef float f32x16 __attribute__((ext_vector_type(16)));
typedef unsigned uint4v __attribute__((ext_vector_type(4)));

static __device__ __forceinline__ float bf2f(unsigned short h) {
  union { unsigned u; float f; } v; v.u = ((unsigned)h) << 16; return v.f;
}
static __device__ __forceinline__ unsigned short f2bf(float f) {
  union { float f; unsigned u; } v; v.f = f;
  unsigned r = v.u + 0x7FFFu + ((v.u >> 16) & 1u);
  return (unsigned short)(r >> 16);
}
static __device__ __forceinline__ float fp_nl(float v) {  // clip(leaky_relu(v),-1,1)
  float t = fmaxf(v, 0.01f * v);
  return fminf(1.f, fmaxf(-1.f, t));
}
static __device__ __forceinline__ unsigned pkbf(float lo, float hi) {
  unsigned r;
  asm("v_cvt_pk_bf16_f32 %0, %1, %2" : "=v"(r) : "v"(lo), "v"(hi));
  return r;
}
// verified R2: swaps 32-lane halves between a,b (a<-{A.lo,B.lo}, b<-{A.hi,B.hi})
static __device__ __forceinline__ void swap32(unsigned &a, unsigned &b) {
  asm("s_nop 1\n\tv_permlane32_swap_b32 %0, %1" : "+v"(a), "+v"(b));
}
static __device__ __forceinline__ uint4v mk4(unsigned a, unsigned b, unsigned c, unsigned d) {
  uint4v v; v[0] = a; v[1] = b; v[2] = c; v[3] = d; return v;
}
static __device__ __forceinline__ short8 u4s8(uint4v w) {
  union { uint4v u; short8 s; } x; x.u = w; return x.s;
}

__global__ void tem_init_m(const float* __restrict__ Min, float* __restrict__ oM) {
  int i = blockIdx.x * 256 + threadIdx.x;
  if (i < PD * PD) oM[i] = LAMDA * Min[i];
}

// ---- macro machinery: all fragment state in NAMED registers, literal indices
#define LDMS(nt, kc) (*(const short8*)(Ms + (((nt) * 32 + cl) * MS_KS + (kc) * 16 + hi * 8)))

// sched_barrier(0) at end of each STEP: bounds the scheduler's in-flight
// window to one STEP (7 ds_read_b128 = 28 VGPRs of A-frags). Without it,
// LLVM clusters loads across the 91-MFMA body -> live state > 256 -> per-
// iteration acc spill to scratch (R5: 860 MB excess HBM writes).
#define STEP(PF, KC) do { \
  const short8 _b = u4s8(PF); \
  acc0 = __builtin_amdgcn_mfma_f32_32x32x16_bf16(LDMS(0, KC), _b, acc0, 0, 0, 0); \
  acc1 = __builtin_amdgcn_mfma_f32_32x32x16_bf16(LDMS(1, KC), _b, acc1, 0, 0, 0); \
  acc2 = __builtin_amdgcn_mfma_f32_32x32x16_bf16(LDMS(2, KC), _b, acc2, 0, 0, 0); \
  acc3 = __builtin_amdgcn_mfma_f32_32x32x16_bf16(LDMS(3, KC), _b, acc3, 0, 0, 0); \
  acc4 = __builtin_amdgcn_mfma_f32_32x32x16_bf16(LDMS(4, KC), _b, acc4, 0, 0, 0); \
  acc5 = __builtin_amdgcn_mfma_f32_32x32x16_bf16(LDMS(5, KC), _b, acc5, 0, 0, 0); \
  acc6 = __builtin_amdgcn_mfma_f32_32x32x16_bf16(LDMS(6, KC), _b, acc6, 0, 0, 0); \
  __builtin_amdgcn_sched_barrier(0); \
} while (0)

#define REPACK_LO(ACC, PF) do { \
  unsigned P0 = pkbf(fp_nl(ACC[0]), fp_nl(ACC[1])); \
  unsigned P1 = pkbf(fp_nl(ACC[2]), fp_nl(ACC[3])); \
  unsigned P2 = pkbf(fp_nl(ACC[4]), fp_nl(ACC[5])); \
  unsigned P3 = pkbf(fp_nl(ACC[6]), fp_nl(ACC[7])); \
  swap32(P0, P2); swap32(P1, P3); \
  PF = mk4(P0, P1, P2, P3); \
} while (0)

#define REPACK_HI(ACC, PF) do { \
  unsigned P4 = pkbf(fp_nl(ACC[8]),  fp_nl(ACC[9])); \
  unsigned P5 = pkbf(fp_nl(ACC[10]), fp_nl(ACC[11])); \
  unsigned P6 = pkbf(fp_nl(ACC[12]), fp_nl(ACC[13])); \
  unsigned P7 = pkbf(fp_nl(ACC[14]), fp_nl(ACC[15])); \
  swap32(P4, P6); swap32(P5, P7); \
  PF = mk4(P4, P5, P6, P7); \
} while (0)

// lane (hi,cl) holds features BB..BB+7 of fragment PF, BB = kc*16 (+8 if hi)
#define FOR_LO(M_) M_(pf0,0) M_(pf1,16) M_(pf2,32) M_(pf3,48) M_(pf4,64) M_(pf5,80) \
                   M_(pf6,96) M_(pf7,112) M_(pf8,128) M_(pf9,144) M_(pf10,160) M_(pf11,176) M_(pf12,192)
#define FOR_HI(M_) M_(pf0,8) M_(pf1,24) M_(pf2,40) M_(pf3,56) M_(pf4,72) M_(pf5,88) \
                   M_(pf6,104) M_(pf7,120) M_(pf8,136) M_(pf9,152) M_(pf10,168) M_(pf11,184)
// hi-branch: pf12 would be features 200..207 (zero pad) -> set to 0 / skipped in epilogues

#define INX(PF, BB) PF = mk4( \
  pkbf(xcv[((BB) + 0) % 10], xcv[((BB) + 1) % 10]), \
  pkbf(xcv[((BB) + 2) % 10], xcv[((BB) + 3) % 10]), \
  pkbf(xcv[((BB) + 4) % 10], xcv[((BB) + 5) % 10]), \
  pkbf(xcv[((BB) + 6) % 10], xcv[((BB) + 7) % 10]));
#define ING(PF, BB) PF = mk4( \
  pkbf(g2v[((BB) + 0) / 10], g2v[((BB) + 1) / 10]), \
  pkbf(g2v[((BB) + 2) / 10], g2v[((BB) + 3) / 10]), \
  pkbf(g2v[((BB) + 4) / 10], g2v[((BB) + 5) / 10]), \
  pkbf(g2v[((BB) + 6) / 10], g2v[((BB) + 7) / 10]));

#define E1W(W, F) { bins[(F) / 10] += bf2f((unsigned short)((W) & 0xFFFFu)); \
                    bins[((F) + 1) / 10] += bf2f((unsigned short)((W) >> 16)); }
#define E1PF(PF, BB) { E1W(PF[0], (BB) + 0) E1W(PF[1], (BB) + 2) E1W(PF[2], (BB) + 4) E1W(PF[3], (BB) + 6) }

#define E2AW(W, F) { ta[(F) % 10] += bf2f((unsigned short)((W) & 0xFFFFu)); \
                     ta[((F) + 1) % 10] += bf2f((unsigned short)((W) >> 16)); }
#define E2APF(PF, BB) { E2AW(PF[0], (BB) + 0) E2AW(PF[1], (BB) + 2) E2AW(PF[2], (BB) + 4) E2AW(PF[3], (BB) + 6) }

#define E2BW(W, F) { \
  const float p0_ = bf2f((unsigned short)((W) & 0xFFFFu)); \
  const float p1_ = bf2f((unsigned short)((W) >> 16)); \
  const float q0_ = fp_nl(g2v[(F) / 10] * xcv[(F) % 10]); \
  const float q1_ = fp_nl(g2v[((F) + 1) / 10] * xcv[((F) + 1) % 10]); \
  dWp[(size_t)(F) * B_TOTAL + r] = f2bf(q0_ - p0_); \
  sWp[(size_t)(F) * B_TOTAL + r] = f2bf(q0_ + p0_); \
  dWp[(size_t)((F) + 1) * B_TOTAL + r] = f2bf(q1_ - p1_); \
  sWp[(size_t)((F) + 1) * B_TOTAL + r] = f2bf(q1_ + p1_); \
}
#define E2BPF(PF, BB) { E2BW(PF[0], (BB) + 0) E2BW(PF[1], (BB) + 2) E2BW(PF[2], (BB) + 4) E2BW(PF[3], (BB) + 6) }

// 256 threads (4 waves): 1 wave/SIMD -> full unified reg budget (R1: 208 VGPR,
// no scratch). 512-thr blocks pinned the compiler to 128 VGPR (R2-R4 spill).
__global__ __launch_bounds__(256, 1) void tem_main(
    const float* __restrict__ xin, const float* __restrict__ gin,
    const float* __restrict__ Min, const float* __restrict__ Wc,
    const float* __restrict__ W1ie, const float* __restrict__ b1ie,
    const float* __restrict__ W2ie, const float* __restrict__ b2ie,
    const float* __restrict__ W1gg, const float* __restrict__ b1gg,
    const float* __restrict__ W2gg, const float* __restrict__ b2gg,
    const float* __restrict__ Wsp, const float* __restrict__ bsp,
    float* __restrict__ o_ginf, float* __restrict__ o_xinf,
    float* __restrict__ o_g, float* __restrict__ o_x,
    unsigned short* __restrict__ dWp, unsigned short* __restrict__ sWp) {
  // LDS: 96768 + 2560 + 10240 = 109568 B
  __shared__ __attribute__((aligned(16))) unsigned short Ms[224 * MS_KS];
  __shared__ unsigned short xcS[128 * 10];
  __shared__ float g2S[128 * 20];

  const int tid = threadIdx.x;
  const int lane = tid & 63;
  const int wid = tid >> 6;      // 0..3
  const int cl = lane & 31;
  const int hi = lane >> 5;
  const int r0 = blockIdx.x * 128;

  {
    unsigned* Ms32 = (unsigned*)Ms;
    for (int i = tid; i < 224 * MS_KS / 2; i += 256) Ms32[i] = 0u;
  }
  __syncthreads();
  for (int i = tid; i < 200 * 224; i += 256) {
    const int k = i / 224, n = i - k * 224;
    if (n < 200) {
      float v = Min[k * 200 + n];
      if (k == n) v += KAPPA;
      Ms[n * MS_KS + k] = f2bf(v);
    }
  }

  // prologue: threads 0..127 -> g2 MLP; 128..255 -> xc
  if (tid < 128) {
    const int r = r0 + tid;
    float gv[20];
#pragma unroll
    for (int i = 0; i < 20; ++i) gv[i] = gin[(size_t)r * 20 + i];
    float h[40];
#pragma unroll
    for (int u = 0; u < 40; ++u) h[u] = b1gg[u];
#pragma unroll
    for (int i = 0; i < 20; ++i)
#pragma unroll
      for (int u = 0; u < 40; ++u) h[u] += gv[i] * W1gg[i * 40 + u];
#pragma unroll
    for (int u = 0; u < 40; ++u) h[u] = (h[u] > 0.f) ? h[u] : (expf(h[u]) - 1.f);
#pragma unroll
    for (int o = 0; o < 20; ++o) {
      float v = b2gg[o];
#pragma unroll
      for (int u = 0; u < 40; ++u) v += h[u] * W2gg[u * 20 + o];
      g2S[tid * 20 + o] = tanhf(v);
    }
  } else {
    const int rr2 = tid - 128;
    const int r = r0 + rr2;
    float xc[10];
#pragma unroll
    for (int o = 0; o < 10; ++o) xc[o] = 0.f;
    for (int j = 0; j < 45; ++j) {
      const float xv = xin[(size_t)r * 45 + j];
#pragma unroll
      for (int o = 0; o < 10; ++o) xc[o] += xv * Wc[j * 10 + o];
    }
#pragma unroll
    for (int o = 0; o < 10; ++o) xcS[rr2 * 10 + o] = f2bf(xc[o]);
  }
  __syncthreads();

  // P1: write g_ and x_ outputs
  for (int i = tid; i < 128 * 200; i += 256) {
    const int rP = i / 200, j = i - rP * 200;
    o_g[(size_t)(r0 + rP) * 200 + j] = g2S[rP * 20 + j / 10];
    o_x[(size_t)(r0 + rP) * 200 + j] = bf2f(xcS[rP * 10 + (j % 10)]);
  }

  const int rr = wid * 32 + cl;   // block-row this lane owns (0..127)
  const int r = r0 + rr;          // global row

  uint4v pf0, pf1, pf2, pf3, pf4, pf5, pf6, pf7, pf8, pf9, pf10, pf11, pf12;

#pragma unroll 1
  for (int ret = 0; ret < 2; ++ret) {
    // ---- build initial fragments (named regs, literal indices)
    if (ret == 0) {
      float xcv[10];
#pragma unroll
      for (int o = 0; o < 10; ++o) xcv[o] = bf2f(xcS[rr * 10 + o]);
      if (hi == 0) { FOR_LO(INX) }
      else         { FOR_HI(INX) pf12 = mk4(0u, 0u, 0u, 0u); }
    } else {
      float g2v[20];
#pragma unroll
      for (int o = 0; o < 20; ++o) g2v[o] = g2S[rr * 20 + o];
      if (hi == 0) { FOR_LO(ING) }
      else         { FOR_HI(ING) pf12 = mk4(0u, 0u, 0u, 0u); }
    }

    // ---- 5 attractor iterations, fully register-resident
#pragma unroll 1
    for (int it = 0; it < 5; ++it) {
      f32x16 acc0 = {}, acc1 = {}, acc2 = {}, acc3 = {}, acc4 = {}, acc5 = {}, acc6 = {};
      STEP(pf0, 0);  STEP(pf1, 1);  STEP(pf2, 2);  STEP(pf3, 3);
      STEP(pf4, 4);  STEP(pf5, 5);  STEP(pf6, 6);  STEP(pf7, 7);
      STEP(pf8, 8);  STEP(pf9, 9);  STEP(pf10, 10); STEP(pf11, 11);
      STEP(pf12, 12);
      REPACK_LO(acc0, pf0);  REPACK_HI(acc0, pf1);
      REPACK_LO(acc1, pf2);  REPACK_HI(acc1, pf3);
      REPACK_LO(acc2, pf4);  REPACK_HI(acc2, pf5);
      REPACK_LO(acc3, pf6);  REPACK_HI(acc3, pf7);
      REPACK_LO(acc4, pf8);  REPACK_HI(acc4, pf9);
      REPACK_LO(acc5, pf10); REPACK_HI(acc5, pf11);
      REPACK_LO(acc6, pf12);              // hi half of tile 6 (n=208..223) dropped
    }

    if (ret == 0) {
      // ---- E1: g_inf = clip(MLP(px @ W_repeat^T))
      float bins[20];
#pragma unroll
      for (int t = 0; t < 20; ++t) bins[t] = 0.f;
      if (hi == 0) { FOR_LO(E1PF) } else { FOR_HI(E1PF) }
#pragma unroll
      for (int t = 0; t < 20; ++t) bins[t] += __shfl_xor(bins[t], 32);
      float h[40];
#pragma unroll
      for (int u = 0; u < 40; ++u) h[u] = b1ie[u];
#pragma unroll
      for (int gg = 0; gg < 20; ++gg) {
        const float bv = bins[gg];
#pragma unroll
        for (int u = 0; u < 40; ++u) h[u] += bv * W1ie[gg * 40 + u];
      }
#pragma unroll
      for (int u = 0; u < 40; ++u) h[u] = (h[u] > 0.f) ? h[u] : (expf(h[u]) - 1.f);
#pragma unroll
      for (int oi = 0; oi < 10; ++oi) {
        const int o = hi * 10 + oi;
        float v = b2ie[o];
#pragma unroll
        for (int u = 0; u < 40; ++u) v += h[u] * W2ie[u * 20 + o];
        o_ginf[(size_t)r * 20 + o] = fminf(1.f, fmaxf(-1.f, v));
      }
    } else {
      // ---- E2a: x_inf = (p @ W_tile^T) @ W_sp + b_sp
      float ta[10];
#pragma unroll
      for (int t = 0; t < 10; ++t) ta[t] = 0.f;
      if (hi == 0) { FOR_LO(E2APF) } else { FOR_HI(E2APF) }
#pragma unroll
      for (int t = 0; t < 10; ++t) ta[t] += __shfl_xor(ta[t], 32);
      {
        const int o0 = hi ? 23 : 0, o1 = hi ? 45 : 23;
        for (int o = o0; o < o1; ++o) {
          float v = bsp[o];
#pragma unroll
          for (int a = 0; a < 10; ++a) v += ta[a] * Wsp[a * 45 + o];
          o_xinf[(size_t)r * 45 + o] = v;
        }
      }
      // ---- E2b: d/s staging, feature-major [f*B + r]
      {
        float xcv[10], g2v[20];
#pragma unroll
        for (int o = 0; o < 10; ++o) xcv[o] = bf2f(xcS[rr * 10 + o]);
#pragma unroll
        for (int o = 0; o < 20; ++o) g2v[o] = g2S[rr * 20 + o];
        if (hi == 0) { FOR_LO(E2BPF) } else { FOR_HI(E2BPF) }
      }
    }
  }
}

__global__ __launch_bounds__(448, 1) void tem_hebb(
    const unsigned short* __restrict__ dWp, const unsigned short* __restrict__ sWp,
    float* __restrict__ oM) {
  const int tid = threadIdx.x;
  const int lane = tid & 63, wid = tid >> 6;   // 7 waves
  const int cl = lane & 31, hi = lane >> 5;
  f32x16 hacc[7];
#pragma unroll
  for (int nt = 0; nt < 7; ++nt)
#pragma unroll
    for (int q = 0; q < 16; ++q) hacc[nt][q] = 0.f;

  const int fa = wid * 32 + cl;
  const size_t arow = (size_t)fa * B_TOTAL;
  const int kb0 = blockIdx.x * 512;
  const short8 zf = {0, 0, 0, 0, 0, 0, 0, 0};

  for (int kch = 0; kch < 32; ++kch) {
    const int kb = kb0 + kch * 16 + hi * 8;
    short8 a = zf;
    if (fa < 200) a = *(const short8*)(dWp + arow + kb);
#pragma unroll
    for (int nt = 0; nt < 7; ++nt) {
      const int fb = nt * 32 + cl;
      short8 b = zf;
      if (fb < 200) b = *(const short8*)(sWp + (size_t)fb * B_TOTAL + kb);
      hacc[nt] = __builtin_amdgcn_mfma_f32_32x32x16_bf16(a, b, hacc[nt], 0, 0, 0);
    }
  }
  const float scale = YITA / (float)B_TOTAL;
#pragma unroll
  for (int nt = 0; nt < 7; ++nt) {
    const int j = nt * 32 + cl;
    if (j < 200) {
#pragma unroll
      for (int rg = 0; rg < 16; ++rg) {
        const int ii = wid * 32 + (rg & 3) + 8 * (rg >> 2) + 4 * hi;
        if (ii < 200) atomicAdd(&oM[ii * 200 + j], hacc[nt][rg] * scale);
      }
    }
  }
}

extern "C" void kernel_launch(void* const* d_in, const int* in_sizes, int n_in,
                              void* d_out, int out_size, void* d_ws, size_t ws_size,
                              hipStream_t stream) {
  (void)in_sizes; (void)n_in; (void)out_size; (void)ws_size;
  const float* xin  = (const float*)d_in[0];
  const float* gin  = (const float*)d_in[1];
  const float* Min  = (const float*)d_in[2];
  const float* Wc   = (const float*)d_in[3];
  const float* W1ie = (const float*)d_in[4];
  const float* b1ie = (const float*)d_in[5];
  const float* W2ie = (const float*)d_in[6];
  const float* b2ie = (const float*)d_in[7];
  const float* W1gg = (const float*)d_in[8];
  const float* b1gg = (const float*)d_in[9];
  const float* W2gg = (const float*)d_in[10];
  const float* b2gg = (const float*)d_in[11];
  const float* Wsp  = (const float*)d_in[12];
  const float* bsp  = (const float*)d_in[13];

  float* out = (float*)d_out;
  float* o_ginf = out;
  float* o_xinf = out + (size_t)B_TOTAL * 20;
  float* o_g    = out + (size_t)B_TOTAL * 65;
  float* o_x    = out + (size_t)B_TOTAL * 265;
  float* o_M    = out + (size_t)B_TOTAL * 465;

  unsigned short* dWp = (unsigned short*)d_ws;
  unsigned short* sWp = dWp + (size_t)PD * B_TOTAL;

  tem_init_m<<<(PD * PD + 255) / 256, 256, 0, stream>>>(Min, o_M);
  tem_main<<<1024, 256, 0, stream>>>(xin, gin, Min, Wc, W1ie, b1ie, W2ie, b2ie,
                                     W1gg, b1gg, W2gg, b2gg, Wsp, bsp,
                                     o_ginf, o_xinf, o_g, o_x, dWp, sWp);
  tem_hebb<<<256, 448, 0, stream>>>(dWp, sWp, o_M);
}